// Round 3
// baseline (102.043 us; speedup 1.0000x reference)
//
#include <hip/hip_runtime.h>
#include <hip/hip_cooperative_groups.h>

namespace cg = cooperative_groups;

namespace {
constexpr int B = 4, Te = 512, Td = 128, Den = 256, Dde = 512, U = 128;
constexpr float REMOVE = 1000000.0f;
constexpr float L2E2 = 2.885390081777927f;  // 2*log2(e)

__device__ __forceinline__ unsigned short f2bf(float f) {
  unsigned u = __float_as_uint(f);
  u += 0x7FFFu + ((u >> 16) & 1u);      // RNE
  return (unsigned short)(u >> 16);
}
__device__ __forceinline__ float bf2f(unsigned short h) {
  return __uint_as_float(((unsigned)h) << 16);
}
// acc += tanh(ep+dv)*nv ; tanh via 1 - 2/(exp(2x)+1), inf-safe both tails
__device__ __forceinline__ void tanh_fma(float ep, float dv, float nv, float& acc) {
  float e = __builtin_amdgcn_exp2f((ep + dv) * L2E2);
  float r = __builtin_amdgcn_rcpf(e + 1.0f);
  acc = fmaf(fmaf(-2.0f, r, 1.0f), nv, acc);
}
__device__ __forceinline__ void fma4(const float4& w, float x, float* a) {
  a[0] = fmaf(x, w.x, a[0]); a[1] = fmaf(x, w.y, a[1]);
  a[2] = fmaf(x, w.z, a[2]); a[3] = fmaf(x, w.w, a[3]);
}

// One cooperative kernel: grid 256 x 512 threads (1 block/CU).
// Phase A: en_p (transposed) + masked bf16 en copy + de_p.  grid.sync.
// Phase BC: per (b, td-pair): scores -> softmax -> weighted sum -> output.
__global__ __launch_bounds__(512) void fused(
    const float* __restrict__ en_seq, const float* __restrict__ de_seq,
    const int* __restrict__ mask, const float* __restrict__ w_en,
    const float* __restrict__ w_de, const float* __restrict__ nu,
    float* __restrict__ en_pT, float* __restrict__ de_p,
    unsigned short* __restrict__ en_bf, float* __restrict__ out) {
  __shared__ float sm[6144];            // 24 KiB
  float* xs  = sm;                      // [0..2047]   staging
  float* red = sm + 2048;               // [2048..6143] 4096f reduce buffer
  const int tid = threadIdx.x;
  const int blk = blockIdx.x;

  //================ PHASE A ================
  {
    const int r0 = blk * 8;             // 8 encoder rows (global b*Te+te)
    {                                   // stage masked rows + bf16 copy
      int row = tid >> 6, c4 = tid & 63;
      float m = (float)mask[r0 + row];
      float4 v = *(const float4*)(en_seq + (size_t)(r0 + row) * Den + c4 * 4);
      v.x *= m; v.y *= m; v.z *= m; v.w *= m;
      *(float4*)(xs + row * 256 + c4 * 4) = v;
      ushort4 h;
      h.x = f2bf(v.x); h.y = f2bf(v.y); h.z = f2bf(v.z); h.w = f2bf(v.w);
      *(ushort4*)(en_bf + (size_t)(r0 + row) * Den + c4 * 4) = h;
    }
    __syncthreads();
    {                                   // en GEMM: 2 rows x 4u, k-split 4
      const int ug = tid & 31, ks = (tid >> 5) & 3, rg = tid >> 7;
      const int u0 = ug * 4, k0 = ks * 64;
      float a0[4] = {0,0,0,0}, a1[4] = {0,0,0,0};
#pragma unroll 4
      for (int k = k0; k < k0 + 64; k += 4) {
        const float* wp = w_en + (size_t)k * U + u0;
        float4 w0 = *(const float4*)(wp);
        float4 w1 = *(const float4*)(wp + U);
        float4 w2 = *(const float4*)(wp + 2 * U);
        float4 w3 = *(const float4*)(wp + 3 * U);
        float4 x0 = *(const float4*)(xs + (rg * 2 + 0) * 256 + k);
        float4 x1 = *(const float4*)(xs + (rg * 2 + 1) * 256 + k);
        fma4(w0, x0.x, a0); fma4(w1, x0.y, a0); fma4(w2, x0.z, a0); fma4(w3, x0.w, a0);
        fma4(w0, x1.x, a1); fma4(w1, x1.y, a1); fma4(w2, x1.z, a1); fma4(w3, x1.w, a1);
      }
      *(float4*)(red + (ks * 8 + rg * 2 + 0) * 128 + u0) = make_float4(a0[0], a0[1], a0[2], a0[3]);
      *(float4*)(red + (ks * 8 + rg * 2 + 1) * 128 + u0) = make_float4(a1[0], a1[1], a1[2], a1[3]);
    }
    __syncthreads();
#pragma unroll
    for (int j = 0; j < 2; ++j) {       // k-reduce + transposed write
      int f = tid * 2 + j;
      int row = f >> 7, u = f & 127;
      float v = red[(0 + row) * 128 + u] + red[(8 + row) * 128 + u] +
                red[(16 + row) * 128 + u] + red[(24 + row) * 128 + u];
      int gr = r0 + row;
      en_pT[((size_t)(gr >> 9) * U + u) * Te + (gr & 511)] = v;
    }
    if (tid < 256) {                    // stage 2 decoder rows (overlaps above)
      int row = tid >> 7, c4 = tid & 127;
      *(float4*)(xs + row * 512 + c4 * 4) =
          *(const float4*)(de_seq + (size_t)(blk * 2 + row) * Dde + c4 * 4);
    }
    __syncthreads();
    {                                   // de GEMM: 2 rows x 4u, k-split 16
      const int ug = tid & 31, ks = tid >> 5;
      const int u0 = ug * 4, k0 = ks * 32;
      float a0[4] = {0,0,0,0}, a1[4] = {0,0,0,0};
#pragma unroll 4
      for (int k = k0; k < k0 + 32; k += 4) {
        const float* wp = w_de + (size_t)k * U + u0;
        float4 w0 = *(const float4*)(wp);
        float4 w1 = *(const float4*)(wp + U);
        float4 w2 = *(const float4*)(wp + 2 * U);
        float4 w3 = *(const float4*)(wp + 3 * U);
        float4 x0 = *(const float4*)(xs + k);
        float4 x1 = *(const float4*)(xs + 512 + k);
        fma4(w0, x0.x, a0); fma4(w1, x0.y, a0); fma4(w2, x0.z, a0); fma4(w3, x0.w, a0);
        fma4(w0, x1.x, a1); fma4(w1, x1.y, a1); fma4(w2, x1.z, a1); fma4(w3, x1.w, a1);
      }
      *(float4*)(red + (ks * 2 + 0) * 128 + u0) = make_float4(a0[0], a0[1], a0[2], a0[3]);
      *(float4*)(red + (ks * 2 + 1) * 128 + u0) = make_float4(a1[0], a1[1], a1[2], a1[3]);
    }
    __syncthreads();
    if (tid < 256) {
      int row = tid >> 7, u = tid & 127;
      float v = 0.f;
#pragma unroll
      for (int ksj = 0; ksj < 16; ++ksj) v += red[(ksj * 2 + row) * 128 + u];
      de_p[(size_t)(blk * 2 + row) * U + u] = v;
    }
  }
  __threadfence();
  cg::this_grid().sync();

  //================ PHASE BC ================
  const int b = blk >> 6;
  const int gtd0 = blk * 2;             // global decoder row pair
  float* dep = sm;                      // [2][128]
  float* nus = sm + 256;                // [128]
  float* mbs = sm + 384;                // [512] mask bias
  float* als = sm + 896;                // [512][2] alphas
  float* scr = sm + 2048;               // [4][2][512] partials / [8][2][256]
  {
    if (tid < 64) {
      int r = tid >> 5, q = tid & 31;
      *(float4*)(dep + r * 128 + q * 4) =
          *(const float4*)(de_p + (size_t)(gtd0 + r) * U + q * 4);
    } else if (tid < 96) {
      int q = tid - 64;
      *(float4*)(nus + q * 4) = *(const float4*)(nu + q * 4);
    }
    mbs[tid] = ((float)mask[b * Te + tid] - 1.0f) * REMOVE;
    __syncthreads();

    // ---- scores: thread = (4 te) x (u-quarter), 2 td ----
    const int ts = tid & 127, uh = tid >> 7;
    const int te0 = ts * 4;
    float s00=0,s01=0,s02=0,s03=0, s10=0,s11=0,s12=0,s13=0;
    const float* ept = en_pT + (size_t)b * U * Te;
#pragma unroll 4
    for (int u = uh * 32; u < uh * 32 + 32; ++u) {
      float4 ev = *(const float4*)(ept + (size_t)u * Te + te0);
      float dv0 = dep[u], dv1 = dep[128 + u], nv = nus[u];
      tanh_fma(ev.x, dv0, nv, s00); tanh_fma(ev.x, dv1, nv, s10);
      tanh_fma(ev.y, dv0, nv, s01); tanh_fma(ev.y, dv1, nv, s11);
      tanh_fma(ev.z, dv0, nv, s02); tanh_fma(ev.z, dv1, nv, s12);
      tanh_fma(ev.w, dv0, nv, s03); tanh_fma(ev.w, dv1, nv, s13);
    }
    *(float4*)(scr + (uh * 2 + 0) * 512 + te0) = make_float4(s00, s01, s02, s03);
    *(float4*)(scr + (uh * 2 + 1) * 512 + te0) = make_float4(s10, s11, s12, s13);
    __syncthreads();

    // ---- softmax (waves 0,1) ; de_seq copy-through (waves 4-7) ----
    const int wid = tid >> 6, lane = tid & 63;
    if (wid < 2) {
      float v[8]; float mx = -3.0e38f;
#pragma unroll
      for (int i = 0; i < 8; ++i) {
        int te = lane + i * 64;
        float s = scr[(0 + wid) * 512 + te] + scr[(2 + wid) * 512 + te] +
                  scr[(4 + wid) * 512 + te] + scr[(6 + wid) * 512 + te] + mbs[te];
        v[i] = s; mx = fmaxf(mx, s);
      }
#pragma unroll
      for (int o = 32; o >= 1; o >>= 1) mx = fmaxf(mx, __shfl_xor(mx, o));
      float ssum = 0.f;
#pragma unroll
      for (int i = 0; i < 8; ++i) { v[i] = __expf(v[i] - mx); ssum += v[i]; }
#pragma unroll
      for (int o = 32; o >= 1; o >>= 1) ssum += __shfl_xor(ssum, o);
      float inv = 1.0f / ssum;
#pragma unroll
      for (int i = 0; i < 8; ++i) als[(lane + i * 64) * 2 + wid] = v[i] * inv;
    } else if (wid >= 4) {
      int o = tid - 256;
      int r = o >> 7, c4 = o & 127;
      *(float4*)(out + (size_t)(gtd0 + r) * 768 + c4 * 4) =
          *(const float4*)(de_seq + (size_t)(gtd0 + r) * Dde + c4 * 4);
    }
    __syncthreads();

    // ---- weighted sum: wave = te-octave, lane = 4 channels ----
    const unsigned short* ebf = en_bf + (size_t)b * Te * Den;
    const int ch0 = lane * 4;
    float p00=0,p01=0,p02=0,p03=0, p10=0,p11=0,p12=0,p13=0;
#pragma unroll 4
    for (int t = 0; t < 64; ++t) {
      int te = wid * 64 + t;
      ushort4 h = *(const ushort4*)(ebf + (size_t)te * Den + ch0);
      float2 al = *(const float2*)(als + te * 2);
      float e0 = bf2f(h.x), e1 = bf2f(h.y), e2 = bf2f(h.z), e3 = bf2f(h.w);
      p00 = fmaf(al.x, e0, p00); p01 = fmaf(al.x, e1, p01);
      p02 = fmaf(al.x, e2, p02); p03 = fmaf(al.x, e3, p03);
      p10 = fmaf(al.y, e0, p10); p11 = fmaf(al.y, e1, p11);
      p12 = fmaf(al.y, e2, p12); p13 = fmaf(al.y, e3, p13);
    }
    *(float4*)(scr + (wid * 2 + 0) * 256 + ch0) = make_float4(p00, p01, p02, p03);
    *(float4*)(scr + (wid * 2 + 1) * 256 + ch0) = make_float4(p10, p11, p12, p13);
    __syncthreads();
    {
      int td = tid >> 8, ch = tid & 255;
      float v = 0.f;
#pragma unroll
      for (int w = 0; w < 8; ++w) v += scr[(w * 2 + td) * 256 + ch];
      out[(size_t)(gtd0 + td) * 768 + 512 + ch] = v;
    }
  }
}
} // namespace

extern "C" void kernel_launch(void* const* d_in, const int* in_sizes, int n_in,
                              void* d_out, int out_size, void* d_ws, size_t ws_size,
                              hipStream_t stream) {
  const float* en_seq = (const float*)d_in[0];
  const float* de_seq = (const float*)d_in[1];
  const int*   mask   = (const int*)d_in[2];
  const float* w_en   = (const float*)d_in[3];
  const float* w_de   = (const float*)d_in[4];
  const float* nu     = (const float*)d_in[5];
  float* out = (float*)d_out;

  float* en_pT = (float*)d_ws;                         // B*U*Te   = 262144 f
  float* de_p  = en_pT + (size_t)B * U * Te;           // B*Td*U   =  65536 f
  unsigned short* en_bf = (unsigned short*)(de_p + (size_t)B * Td * U);  // B*Te*Den bf16

  void* args[] = {(void*)&en_seq, (void*)&de_seq, (void*)&mask, (void*)&w_en,
                  (void*)&w_de,  (void*)&nu,     (void*)&en_pT, (void*)&de_p,
                  (void*)&en_bf, (void*)&out};
  hipLaunchCooperativeKernel((const void*)fused, dim3(256), dim3(512), args, 0, stream);
}

// Round 4
// 41.118 us; speedup vs baseline: 2.4817x; 2.4817x over previous
//
#include <hip/hip_runtime.h>

namespace {
constexpr int B = 4, Te = 512, Td = 128, Den = 256, Dde = 512, U = 128;
constexpr float REMOVE = 1000000.0f;
constexpr float L2E2 = 2.885390081777927f;  // 2*log2(e)

__device__ __forceinline__ unsigned short f2bf(float f) {
  unsigned u = __float_as_uint(f);
  u += 0x7FFFu + ((u >> 16) & 1u);      // RNE
  return (unsigned short)(u >> 16);
}
__device__ __forceinline__ float bf2f(unsigned short h) {
  return __uint_as_float(((unsigned)h) << 16);
}
// acc += tanh(ep+dv)*nv ; tanh = 1 - 2/(exp(2x)+1), inf-safe both tails
__device__ __forceinline__ void tanh_fma(float ep, float dv, float nv, float& acc) {
  float e = __builtin_amdgcn_exp2f((ep + dv) * L2E2);
  float r = __builtin_amdgcn_rcpf(e + 1.0f);
  acc = fmaf(fmaf(-2.0f, r, 1.0f), nv, acc);
}
__device__ __forceinline__ void fma4(const float4& w, float x, float* a) {
  a[0] = fmaf(x, w.x, a[0]); a[1] = fmaf(x, w.y, a[1]);
  a[2] = fmaf(x, w.z, a[2]); a[3] = fmaf(x, w.w, a[3]);
}

// ---------------- K1: projections ----------------
// blocks 0..127: 16 en rows -> en_pT (bf16, [b][u][te]) + masked bf16 en copy
// blocks 128..255: q=blk-128: rt=q>>1 (8 de rows), kh=q&1 (K-half)
//                  -> de_pA/de_pB + de pass-through to out (channel half kh)
__global__ __launch_bounds__(512) void proj_kernel(
    const float* __restrict__ en_seq, const float* __restrict__ de_seq,
    const int* __restrict__ mask, const float* __restrict__ w_en,
    const float* __restrict__ w_de, unsigned short* __restrict__ en_pT,
    unsigned short* __restrict__ en_bf, float* __restrict__ de_pA,
    float* __restrict__ de_pB, float* __restrict__ out) {
  __shared__ float xs[4096];            // 16 KiB
  const int blk = blockIdx.x, tid = threadIdx.x;

  if (blk < 128) {
    const int r0 = blk * 16;            // global encoder rows (b*Te+te)
    for (int i = tid; i < 1024; i += 512) {   // stage masked + bf16 copy
      int row = i >> 6, c4 = i & 63;
      float m = (float)mask[r0 + row];
      float4 v = *(const float4*)(en_seq + (size_t)(r0 + row) * Den + c4 * 4);
      v.x *= m; v.y *= m; v.z *= m; v.w *= m;
      *(float4*)(xs + row * 256 + c4 * 4) = v;
      ushort4 h; h.x = f2bf(v.x); h.y = f2bf(v.y); h.z = f2bf(v.z); h.w = f2bf(v.w);
      *(ushort4*)(en_bf + (size_t)(r0 + row) * Den + c4 * 4) = h;
    }
    __syncthreads();
    const int rg = tid >> 5, ug = tid & 31, u0 = ug * 4;
    float acc[4] = {0, 0, 0, 0};
    for (int k = 0; k < 256; k += 4) {
      const float* wp = w_en + (size_t)k * U + u0;
      float4 w0 = *(const float4*)(wp);
      float4 w1 = *(const float4*)(wp + U);
      float4 w2 = *(const float4*)(wp + 2 * U);
      float4 w3 = *(const float4*)(wp + 3 * U);
      float4 xv = *(const float4*)(xs + rg * 256 + k);
      fma4(w0, xv.x, acc); fma4(w1, xv.y, acc);
      fma4(w2, xv.z, acc); fma4(w3, xv.w, acc);
    }
    __syncthreads();                    // xs reads done; reuse as [128][17]
#pragma unroll
    for (int j = 0; j < 4; ++j) xs[(u0 + j) * 17 + rg] = acc[j];
    __syncthreads();
    {                                   // coalesced transposed bf16 write
      int u = tid >> 2, q = tid & 3;
      const float* p = xs + u * 17 + q * 4;
      ushort4 h; h.x = f2bf(p[0]); h.y = f2bf(p[1]); h.z = f2bf(p[2]); h.w = f2bf(p[3]);
      int b = r0 >> 9, teb = (r0 & 511) + q * 4;
      *(ushort4*)(en_pT + ((size_t)b * U + u) * Te + teb) = h;
    }
  } else {
    const int q = blk - 128, rt = q >> 1, kh = q & 1;
    const int r0 = rt * 8, k0 = kh * 256;   // global decoder rows, K offset
    {                                   // stage K-half + pass-through
      int row = tid >> 6, c4 = tid & 63;
      float4 v = *(const float4*)(de_seq + (size_t)(r0 + row) * Dde + k0 + c4 * 4);
      *(float4*)(xs + row * 256 + c4 * 4) = v;
      *(float4*)(out + (size_t)(r0 + row) * 768 + k0 + c4 * 4) = v;
    }
    __syncthreads();
    const int ks = tid >> 8, rg = (tid >> 5) & 7, ug = tid & 31, u0 = ug * 4;
    float acc[4] = {0, 0, 0, 0};
    for (int k = ks * 128; k < ks * 128 + 128; k += 4) {
      const float* wp = w_de + (size_t)(k0 + k) * U + u0;
      float4 w0 = *(const float4*)(wp);
      float4 w1 = *(const float4*)(wp + U);
      float4 w2 = *(const float4*)(wp + 2 * U);
      float4 w3 = *(const float4*)(wp + 3 * U);
      float4 xv = *(const float4*)(xs + rg * 256 + k);
      fma4(w0, xv.x, acc); fma4(w1, xv.y, acc);
      fma4(w2, xv.z, acc); fma4(w3, xv.w, acc);
    }
    __syncthreads();                    // xs free; reuse as partials [16][128]
    *(float4*)(xs + (ks * 8 + rg) * 128 + u0) =
        make_float4(acc[0], acc[1], acc[2], acc[3]);
    __syncthreads();
    float* dst = kh ? de_pB : de_pA;
    for (int i = tid; i < 1024; i += 512) {
      int r = i >> 7, u = i & 127;
      dst[(size_t)(r0 + r) * U + u] = xs[r * 128 + u] + xs[(8 + r) * 128 + u];
    }
  }
}

// ---------------- K2: scores + softmax + weighted sum ----------------
// grid 256 = (b:4) x (td-pair:64); 512 threads.
__global__ __launch_bounds__(512) void attn_kernel(
    const unsigned short* __restrict__ en_pT, const unsigned short* __restrict__ en_bf,
    const float* __restrict__ de_pA, const float* __restrict__ de_pB,
    const float* __restrict__ nu, const int* __restrict__ mask,
    float* __restrict__ out) {
  __shared__ float dep[256];
  __shared__ float nus[128];
  __shared__ float mbs[512];
  __shared__ float als[1024];           // [te][2]
  __shared__ float scr[4096];           // score partials / sum partials
  const int blk = blockIdx.x, tid = threadIdx.x;
  const int b = blk >> 6, tp = blk & 63;
  const int gtd0 = b * Td + tp * 2;

  mbs[tid] = ((float)mask[b * Te + tid] - 1.0f) * REMOVE;
  if (tid < 64) {
    int r = tid >> 5, q = tid & 31;
    float4 a = *(const float4*)(de_pA + (size_t)(gtd0 + r) * U + q * 4);
    float4 c = *(const float4*)(de_pB + (size_t)(gtd0 + r) * U + q * 4);
    *(float4*)(dep + r * 128 + q * 4) =
        make_float4(a.x + c.x, a.y + c.y, a.z + c.z, a.w + c.w);
  } else if (tid < 96) {
    int q2 = tid - 64;
    *(float4*)(nus + q2 * 4) = *(const float4*)(nu + q2 * 4);
  }
  __syncthreads();

  {                                     // ---- scores ----
    const int ts = tid & 127, uq = tid >> 7;
    const int te0 = ts * 4;
    float s0[4] = {0, 0, 0, 0}, s1[4] = {0, 0, 0, 0};
    const unsigned short* ep = en_pT + (size_t)b * U * Te;
#pragma unroll 4
    for (int u = uq * 32; u < uq * 32 + 32; ++u) {
      ushort4 h = *(const ushort4*)(ep + (size_t)u * Te + te0);
      float dv0 = dep[u], dv1 = dep[128 + u], nv = nus[u];
      float e0 = bf2f(h.x), e1 = bf2f(h.y), e2 = bf2f(h.z), e3 = bf2f(h.w);
      tanh_fma(e0, dv0, nv, s0[0]); tanh_fma(e0, dv1, nv, s1[0]);
      tanh_fma(e1, dv0, nv, s0[1]); tanh_fma(e1, dv1, nv, s1[1]);
      tanh_fma(e2, dv0, nv, s0[2]); tanh_fma(e2, dv1, nv, s1[2]);
      tanh_fma(e3, dv0, nv, s0[3]); tanh_fma(e3, dv1, nv, s1[3]);
    }
    *(float4*)(scr + (uq * 2 + 0) * 512 + te0) = make_float4(s0[0], s0[1], s0[2], s0[3]);
    *(float4*)(scr + (uq * 2 + 1) * 512 + te0) = make_float4(s1[0], s1[1], s1[2], s1[3]);
  }
  __syncthreads();

  {                                     // ---- softmax (waves 0,1) ----
    const int wid = tid >> 6, lane = tid & 63;
    if (wid < 2) {
      float v[8]; float mx = -3.0e38f;
#pragma unroll
      for (int i = 0; i < 8; ++i) {
        int te = lane + i * 64;
        float s = scr[(0 + wid) * 512 + te] + scr[(2 + wid) * 512 + te] +
                  scr[(4 + wid) * 512 + te] + scr[(6 + wid) * 512 + te] + mbs[te];
        v[i] = s; mx = fmaxf(mx, s);
      }
#pragma unroll
      for (int o = 32; o >= 1; o >>= 1) mx = fmaxf(mx, __shfl_xor(mx, o));
      float ssum = 0.f;
#pragma unroll
      for (int i = 0; i < 8; ++i) { v[i] = __expf(v[i] - mx); ssum += v[i]; }
#pragma unroll
      for (int o = 32; o >= 1; o >>= 1) ssum += __shfl_xor(ssum, o);
      float inv = 1.0f / ssum;
#pragma unroll
      for (int i = 0; i < 8; ++i) als[(lane + i * 64) * 2 + wid] = v[i] * inv;
    }
  }
  __syncthreads();

  {                                     // ---- weighted sum ----
    const int wid = tid >> 6, lane = tid & 63;
    const int ch0 = lane * 4;
    const unsigned short* eb = en_bf + (size_t)b * Te * Den;
    float p0[4] = {0, 0, 0, 0}, p1[4] = {0, 0, 0, 0};
#pragma unroll 4
    for (int t = 0; t < 64; ++t) {
      int te = wid * 64 + t;
      ushort4 h = *(const ushort4*)(eb + (size_t)te * Den + ch0);
      float2 al = *(const float2*)(als + te * 2);
      float e0 = bf2f(h.x), e1 = bf2f(h.y), e2 = bf2f(h.z), e3 = bf2f(h.w);
      p0[0] = fmaf(al.x, e0, p0[0]); p0[1] = fmaf(al.x, e1, p0[1]);
      p0[2] = fmaf(al.x, e2, p0[2]); p0[3] = fmaf(al.x, e3, p0[3]);
      p1[0] = fmaf(al.y, e0, p1[0]); p1[1] = fmaf(al.y, e1, p1[1]);
      p1[2] = fmaf(al.y, e2, p1[2]); p1[3] = fmaf(al.y, e3, p1[3]);
    }
    *(float4*)(scr + (wid * 2 + 0) * 256 + ch0) = make_float4(p0[0], p0[1], p0[2], p0[3]);
    *(float4*)(scr + (wid * 2 + 1) * 256 + ch0) = make_float4(p1[0], p1[1], p1[2], p1[3]);
  }
  __syncthreads();

  {
    int td = tid >> 8, ch = tid & 255;
    float v = 0.f;
#pragma unroll
    for (int w = 0; w < 8; ++w) v += scr[(w * 2 + td) * 256 + ch];
    out[(size_t)(gtd0 + td) * 768 + 512 + ch] = v;
  }
}
} // namespace

extern "C" void kernel_launch(void* const* d_in, const int* in_sizes, int n_in,
                              void* d_out, int out_size, void* d_ws, size_t ws_size,
                              hipStream_t stream) {
  const float* en_seq = (const float*)d_in[0];
  const float* de_seq = (const float*)d_in[1];
  const int*   mask   = (const int*)d_in[2];
  const float* w_en   = (const float*)d_in[3];
  const float* w_de   = (const float*)d_in[4];
  const float* nu     = (const float*)d_in[5];
  float* out = (float*)d_out;

  unsigned short* en_pT = (unsigned short*)d_ws;                 // B*U*Te bf16
  unsigned short* en_bf = en_pT + (size_t)B * U * Te;            // B*Te*Den bf16
  float* de_pA = (float*)(en_bf + (size_t)B * Te * Den);         // B*Td*U f32
  float* de_pB = de_pA + (size_t)B * Td * U;                     // B*Td*U f32

  hipLaunchKernelGGL(proj_kernel, dim3(256), dim3(512), 0, stream,
                     en_seq, de_seq, mask, w_en, w_de, en_pT, en_bf,
                     de_pA, de_pB, out);
  hipLaunchKernelGGL(attn_kernel, dim3(256), dim3(512), 0, stream,
                     en_pT, en_bf, de_pA, de_pB, nu, mask, out);
}